// Round 1
// baseline (76.676 us; speedup 1.0000x reference)
//
#include <hip/hip_runtime.h>
#include <hip/hip_bf16.h>

#define DM 1024
#define SD 32
#define NG 8
#define GD 128
#define BS 4
#define TT 4096
#define CL 64        // chunk length
#define NC (TT/CL)   // 64 chunks

typedef __attribute__((ext_vector_type(8))) short short8;
typedef __attribute__((ext_vector_type(4))) float f32x4;

// workspace layout (bytes), all 16B aligned
#define WS_ABAR  0                         // f32[256]
#define WS_POWA  1024                      // f32[8][64][32]  = 64KB  (powA[g][t][n] = Abar^(t+1))
#define WS_BBAR  (WS_POWA + 65536)         // bf16[8][32][128] = 64KB
#define WS_CB    (WS_BBAR + 65536)         // bf16[8][128][32] = 64KB
#define WS_STL   (WS_CB + 65536)           // bf16[4][64][8][64][32] = 8MB (local-scan states)
#define WS_CARRY (WS_STL + 8388608)        // f32[4][64][8][32] = 256KB
#define WS_PREF  (WS_CARRY + 262144)       // f32[4][64][8][32] = 256KB

__device__ __forceinline__ unsigned short f2bf(float f) {
  unsigned u = __float_as_uint(f);
  unsigned r = (u + 0x7FFFu + ((u >> 16) & 1u)) >> 16;   // RNE
  return (unsigned short)r;
}
__device__ __forceinline__ float bf2f(unsigned short h) {
  return __uint_as_float(((unsigned)h) << 16);
}

// ---------------- K0: parameters ----------------
__global__ void k0_params(const float* __restrict__ A_log,
                          const float* __restrict__ B_param,
                          const float* __restrict__ C,
                          const float* __restrict__ dt_logit,
                          unsigned char* __restrict__ ws) {
  const int tid = threadIdx.x;           // 256 = 8g x 32n
  const int g = tid >> 5, n = tid & 31;
  float* Abar = (float*)(ws + WS_ABAR);
  float* powA = (float*)(ws + WS_POWA);
  unsigned short* Bb = (unsigned short*)(ws + WS_BBAR);
  unsigned short* Cb = (unsigned short*)(ws + WS_CB);

  float al = A_log[tid];
  float sp = (al > 20.f) ? al : log1pf(expf(al));   // softplus
  float A = -sp;
  float dl = dt_logit[g];
  float dt = 0.001f + 0.099f * (1.f / (1.f + expf(-dl)));
  float a = expf(A * dt);
  Abar[tid] = a;
  float frac = (fabsf(A) > 1e-6f) ? (a - 1.f) / A : dt;

  float p = 1.f;
  #pragma unroll
  for (int t = 0; t < CL; ++t) { p *= a; powA[(g*CL + t)*SD + n] = p; }

  #pragma unroll
  for (int i = 0; i < GD; ++i)
    Bb[tid*GD + i] = f2bf(frac * B_param[tid*GD + i]);   // [g][n][i]

  #pragma unroll
  for (int k = 0; k < 128; ++k) {
    int idx = tid*128 + k;                                // 32768 = 8*128*32
    Cb[idx] = f2bf(C[idx]);                               // [g][d][n]
  }
  (void)n;
}

// ---------------- K1: Bu GEMM + local scan ----------------
__global__ __launch_bounds__(64, 2) void k1_bu_scan(const float* __restrict__ u,
                                                    unsigned char* __restrict__ ws) {
  const int bx = blockIdx.x;
  const int c = bx & (NC - 1);
  const int g = (bx >> 6) & (NG - 1);
  const int b = bx >> 9;
  const int l = threadIdx.x;

  __shared__ __align__(16) unsigned char sMem[24576];
  unsigned char* sU = sMem;                 // 16KB: bf16 [t=64][i=128], XOR swizzled
  unsigned char* sB = sMem + 16384;         // 8KB:  bf16 [n=32][i=128], XOR swizzled

  // stage u -> bf16 LDS (A operand). 16 passes x (4 rows x 16 i-octets)
  const float* up = u + ((size_t)b*TT + (size_t)c*CL)*DM + g*GD;
  #pragma unroll
  for (int p = 0; p < 16; ++p) {
    int r = p*4 + (l >> 4);
    int i0 = (l & 15) * 8;
    const float* rp = up + (size_t)r*DM + i0;
    float4 v0 = *(const float4*)rp;
    float4 v1 = *(const float4*)(rp + 4);
    short8 h;
    h[0]=(short)f2bf(v0.x); h[1]=(short)f2bf(v0.y); h[2]=(short)f2bf(v0.z); h[3]=(short)f2bf(v0.w);
    h[4]=(short)f2bf(v1.x); h[5]=(short)f2bf(v1.y); h[6]=(short)f2bf(v1.z); h[7]=(short)f2bf(v1.w);
    int byte = (r*256 + i0*2) ^ ((r & 7) << 4);
    *(short8*)(sU + byte) = h;
  }
  // stage Bbar[g] (bf16 [n][i]) -> LDS, swizzled
  const unsigned short* bbp = (const unsigned short*)(ws + WS_BBAR) + g*SD*GD;
  #pragma unroll
  for (int p = 0; p < 8; ++p) {
    int u16 = p*64 + l;               // 512 16B-units
    int n  = u16 >> 4;
    int i0 = (u16 & 15) * 8;
    short8 h = *(const short8*)(bbp + n*GD + i0);
    int byte = (n*256 + i0*2) ^ ((n & 7) << 4);
    *(short8*)(sB + byte) = h;
  }
  __syncthreads();

  // MFMA: M=64(t) x N=32(n) x K=128(i)
  f32x4 acc[4][2];
  #pragma unroll
  for (int m = 0; m < 4; ++m)
    #pragma unroll
    for (int nt = 0; nt < 2; ++nt)
      #pragma unroll
      for (int j = 0; j < 4; ++j) acc[m][nt][j] = 0.f;

  const int lr = l & 15, lh = l >> 4;
  #pragma unroll
  for (int kt = 0; kt < 4; ++kt) {
    int kb = kt*32 + lh*8;
    short8 af[4], bfg[2];
    #pragma unroll
    for (int m = 0; m < 4; ++m) {
      int row = m*16 + lr;
      af[m] = *(short8*)(sU + ((row*256 + kb*2) ^ ((row & 7) << 4)));
    }
    #pragma unroll
    for (int nt = 0; nt < 2; ++nt) {
      int col = nt*16 + lr;
      bfg[nt] = *(short8*)(sB + ((col*256 + kb*2) ^ ((col & 7) << 4)));
    }
    #pragma unroll
    for (int m = 0; m < 4; ++m)
      #pragma unroll
      for (int nt = 0; nt < 2; ++nt)
        acc[m][nt] = __builtin_amdgcn_mfma_f32_16x16x32_bf16(af[m], bfg[nt], acc[m][nt], 0, 0, 0);
  }
  __syncthreads();

  // reuse LDS: Bu f32 [t][33] then states bf16 [t][32]
  float* sBu = (float*)sMem;                         // 8448B
  unsigned short* sSt = (unsigned short*)(sMem + 8448); // 4096B
  #pragma unroll
  for (int m = 0; m < 4; ++m)
    #pragma unroll
    for (int nt = 0; nt < 2; ++nt)
      #pragma unroll
      for (int j = 0; j < 4; ++j) {
        int t = m*16 + lh*4 + j;                     // C/D: row=(lane>>4)*4+j
        int n = nt*16 + lr;                          //       col=lane&15
        sBu[t*33 + n] = acc[m][nt][j];
      }
  __syncthreads();

  // local scan (zero carry) on 32 lanes
  float* carry = (float*)(ws + WS_CARRY);
  if (l < SD) {
    float a = ((const float*)(ws + WS_ABAR))[g*SD + l];
    float s = 0.f;
    #pragma unroll
    for (int t = 0; t < CL; ++t) {
      s = fmaf(s, a, sBu[t*33 + l]);
      sSt[t*SD + l] = f2bf(s);
    }
    carry[((b*NC + c)*NG + g)*SD + l] = s;
  }
  __syncthreads();

  // bulk copy local states -> global (bf16)
  unsigned short* stg = (unsigned short*)(ws + WS_STL) + ((size_t)((b*NC + c)*NG + g))*CL*SD;
  #pragma unroll
  for (int p = 0; p < 4; ++p) {
    int off = (p*64 + l) * 8;      // 2048 ushorts
    *(short8*)(stg + off) = *(short8*)(sSt + off);
  }
}

// ---------------- K2: chunk-prefix scan ----------------
__global__ void k2_prefix(const float* __restrict__ state0,
                          unsigned char* __restrict__ ws,
                          float* __restrict__ out_sfinal) {
  const int b = blockIdx.x;            // 4 blocks
  const int tid = threadIdx.x;         // 256
  const int g = tid >> 5, n = tid & 31;
  const float* carry = (const float*)(ws + WS_CARRY);
  float* pref = (float*)(ws + WS_PREF);
  const float aL = ((const float*)(ws + WS_POWA))[(g*CL + CL - 1)*SD + n]; // a^L

  float ca[NC];
  #pragma unroll
  for (int c = 0; c < NC; ++c)
    ca[c] = carry[((b*NC + c)*NG + g)*SD + n];

  float p = state0[(b*NG + g)*SD + n];
  #pragma unroll
  for (int c = 0; c < NC; ++c) {
    pref[((b*NC + c)*NG + g)*SD + n] = p;   // state entering chunk c
    p = fmaf(p, aL, ca[c]);
  }
  out_sfinal[(b*NG + g)*SD + n] = p;
}

// ---------------- K3: correction + C GEMM + Dp*u + y ----------------
__global__ __launch_bounds__(64, 2) void k3_y(const float* __restrict__ u,
                                              const float* __restrict__ Dp,
                                              unsigned char* __restrict__ ws,
                                              float* __restrict__ y) {
  const int bx = blockIdx.x;
  const int c = bx & (NC - 1);
  const int g = (bx >> 6) & (NG - 1);
  const int b = bx >> 9;
  const int l = threadIdx.x;

  __shared__ __align__(16) unsigned char sA[CL * 64];   // 4KB bf16 [t][n=32], swizzled
  __shared__ __align__(16) unsigned char sC[GD * 64];   // 8KB bf16 [d][n=32], swizzled

  const unsigned short* stg = (const unsigned short*)(ws + WS_STL) + ((size_t)((b*NC + c)*NG + g))*CL*SD;
  const float* powA = (const float*)(ws + WS_POWA) + g*CL*SD;
  const float* pref = (const float*)(ws + WS_PREF) + ((b*NC + c)*NG + g)*SD;

  // stage corrected states: s_true = s_loc + a^(t+1) * prefix
  #pragma unroll
  for (int p = 0; p < 4; ++p) {
    int u16 = p*64 + l;            // 256 16B-units over [t][n]
    int t  = u16 >> 2;
    int n0 = (u16 & 3) * 8;
    short8 sl = *(const short8*)(stg + t*SD + n0);
    float4 pw0 = *(const float4*)(powA + t*SD + n0);
    float4 pw1 = *(const float4*)(powA + t*SD + n0 + 4);
    float4 pf0 = *(const float4*)(pref + n0);
    float4 pf1 = *(const float4*)(pref + n0 + 4);
    short8 h;
    h[0] = (short)f2bf(bf2f((unsigned short)sl[0]) + pw0.x*pf0.x);
    h[1] = (short)f2bf(bf2f((unsigned short)sl[1]) + pw0.y*pf0.y);
    h[2] = (short)f2bf(bf2f((unsigned short)sl[2]) + pw0.z*pf0.z);
    h[3] = (short)f2bf(bf2f((unsigned short)sl[3]) + pw0.w*pf0.w);
    h[4] = (short)f2bf(bf2f((unsigned short)sl[4]) + pw1.x*pf1.x);
    h[5] = (short)f2bf(bf2f((unsigned short)sl[5]) + pw1.y*pf1.y);
    h[6] = (short)f2bf(bf2f((unsigned short)sl[6]) + pw1.z*pf1.z);
    h[7] = (short)f2bf(bf2f((unsigned short)sl[7]) + pw1.w*pf1.w);
    int byte = (t*64 + n0*2) ^ ((t & 7) << 4);
    *(short8*)(sA + byte) = h;
  }
  // stage C[g] (bf16 [d][n]) -> LDS
  const unsigned short* cb = (const unsigned short*)(ws + WS_CB) + g*GD*SD;
  #pragma unroll
  for (int p = 0; p < 8; ++p) {
    int u16 = p*64 + l;            // 512 units
    int d  = u16 >> 2;
    int n0 = (u16 & 3) * 8;
    short8 h = *(const short8*)(cb + d*SD + n0);
    int byte = (d*64 + n0*2) ^ ((d & 7) << 4);
    *(short8*)(sC + byte) = h;
  }
  __syncthreads();

  // MFMA: M=64(t) x N=128(d) x K=32(n), single K-step
  const int lr = l & 15, lh = l >> 4;
  const int kb = lh * 8;
  short8 a_[4];
  #pragma unroll
  for (int m = 0; m < 4; ++m) {
    int row = m*16 + lr;
    a_[m] = *(short8*)(sA + ((row*64 + kb*2) ^ ((row & 7) << 4)));
  }
  f32x4 acc[4][8];
  #pragma unroll
  for (int nt = 0; nt < 8; ++nt) {
    int col = nt*16 + lr;
    short8 b_ = *(short8*)(sC + ((col*64 + kb*2) ^ ((col & 7) << 4)));
    #pragma unroll
    for (int m = 0; m < 4; ++m) {
      f32x4 z;
      #pragma unroll
      for (int j = 0; j < 4; ++j) z[j] = 0.f;
      acc[m][nt] = __builtin_amdgcn_mfma_f32_16x16x32_bf16(a_[m], b_, z, 0, 0, 0);
    }
  }

  // epilogue: y = Cs + Dp * u
  float dp[8];
  #pragma unroll
  for (int nt = 0; nt < 8; ++nt) dp[nt] = Dp[g*GD + nt*16 + lr];

  #pragma unroll
  for (int m = 0; m < 4; ++m)
    #pragma unroll
    for (int j = 0; j < 4; ++j) {
      int t = m*16 + lh*4 + j;
      size_t rowoff = ((size_t)b*TT + (size_t)c*CL + t)*DM + g*GD;
      #pragma unroll
      for (int nt = 0; nt < 8; ++nt) {
        int d = nt*16 + lr;
        y[rowoff + d] = acc[m][nt][j] + dp[nt]*u[rowoff + d];
      }
    }
}

extern "C" void kernel_launch(void* const* d_in, const int* in_sizes, int n_in,
                              void* d_out, int out_size, void* d_ws, size_t ws_size,
                              hipStream_t stream) {
  const float* u       = (const float*)d_in[0];
  const float* state0  = (const float*)d_in[1];
  const float* A_log   = (const float*)d_in[2];
  const float* B_param = (const float*)d_in[3];
  const float* C       = (const float*)d_in[4];
  const float* Dp      = (const float*)d_in[5];
  const float* dtl     = (const float*)d_in[6];
  float* y = (float*)d_out;
  unsigned char* ws = (unsigned char*)d_ws;
  float* sfin = y + (size_t)BS*TT*DM;

  k0_params<<<dim3(1), dim3(256), 0, stream>>>(A_log, B_param, C, dtl, ws);
  k1_bu_scan<<<dim3(BS*NG*NC), dim3(64), 0, stream>>>(u, ws);
  k2_prefix<<<dim3(BS), dim3(256), 0, stream>>>(state0, ws, sfin);
  k3_y<<<dim3(BS*NG*NC), dim3(64), 0, stream>>>(u, Dp, ws, y);
}

// Round 2
// 54.436 us; speedup vs baseline: 1.4086x; 1.4086x over previous
//
#include <hip/hip_runtime.h>
#include <hip/hip_bf16.h>

#define DM 1024
#define SD 32
#define NG 8
#define GD 128
#define BS 4
#define TT 4096
#define CL 64        // chunk length
#define NC (TT/CL)   // 64 chunks

typedef __attribute__((ext_vector_type(8))) short short8;
typedef __attribute__((ext_vector_type(4))) float f32x4;

// workspace layout (bytes), 16B aligned
#define WS_POWA  0                         // f32[8][64][32]  = 64KB  (powA[g][t][n] = Abar^(t+1))
#define WS_STL   65536                     // bf16[4][64][8][64][32] = 8MB (local-scan states)
#define WS_CARRY (WS_STL + 8388608)        // f32[4][64][8][32] = 256KB

__device__ __forceinline__ unsigned short f2bf(float f) {
  unsigned u = __float_as_uint(f);
  unsigned r = (u + 0x7FFFu + ((u >> 16) & 1u)) >> 16;   // RNE
  return (unsigned short)r;
}
__device__ __forceinline__ float bf2f(unsigned short h) {
  return __uint_as_float(((unsigned)h) << 16);
}
__device__ __forceinline__ float softplus_f(float x) {
  return (x > 20.f) ? x : log1pf(expf(x));
}
__device__ __forceinline__ short8 pack8(float4 a, float4 b) {
  short8 h;
  h[0]=(short)f2bf(a.x); h[1]=(short)f2bf(a.y); h[2]=(short)f2bf(a.z); h[3]=(short)f2bf(a.w);
  h[4]=(short)f2bf(b.x); h[5]=(short)f2bf(b.y); h[6]=(short)f2bf(b.z); h[7]=(short)f2bf(b.w);
  return h;
}

// ---------------- KA: Bu GEMM (reg-direct) + local scan (+powA for 8 blocks) ----------------
__global__ __launch_bounds__(64) void ka_bu_scan(const float* __restrict__ u,
                                                 const float* __restrict__ A_log,
                                                 const float* __restrict__ B_param,
                                                 const float* __restrict__ dt_logit,
                                                 unsigned char* __restrict__ ws) {
  const int bx = blockIdx.x;
  const int c = bx & (NC - 1);
  const int g = (bx >> 6) & (NG - 1);
  const int b = bx >> 9;
  const int l = threadIdx.x;
  const int lr = l & 15, lh = l >> 4;

  // dt for this group
  const float dtg = 0.001f + 0.099f * (1.f / (1.f + expf(-dt_logit[g])));

  // frac for the two B-operand n's this lane touches (n = nt*16 + lr)
  float fracv[2];
  #pragma unroll
  for (int nt = 0; nt < 2; ++nt) {
    int n = nt * 16 + lr;
    float A = -softplus_f(A_log[g * SD + n]);
    float a = expf(A * dtg);
    fracv[nt] = (fabsf(A) > 1e-6f) ? (a - 1.f) / A : dtg;
  }
  // scan decay for n = l&31
  float a_scan;
  {
    float A = -softplus_f(A_log[g * SD + (l & 31)]);
    a_scan = expf(A * dtg);
  }

  // B fragments: Bbar[n][i] = frac_n * B_param[g][n][i], n = nt*16+lr, i = kt*32 + lh*8 ..+7
  const float* bp = B_param + (size_t)g * SD * GD;
  short8 bfr[4][2];
  #pragma unroll
  for (int kt = 0; kt < 4; ++kt)
    #pragma unroll
    for (int nt = 0; nt < 2; ++nt) {
      const float* p = bp + (size_t)(nt * 16 + lr) * GD + kt * 32 + lh * 8;
      float4 v0 = *(const float4*)p;
      float4 v1 = *(const float4*)(p + 4);
      float s = fracv[nt];
      v0.x*=s; v0.y*=s; v0.z*=s; v0.w*=s;
      v1.x*=s; v1.y*=s; v1.z*=s; v1.w*=s;
      bfr[kt][nt] = pack8(v0, v1);
    }

  // A fragments streamed from global: u[t][i], t = m*16+lr, i = kt*32+lh*8
  const float* up = u + ((size_t)b * TT + (size_t)c * CL) * DM + g * GD;
  f32x4 acc[4][2];
  #pragma unroll
  for (int m = 0; m < 4; ++m)
    #pragma unroll
    for (int nt = 0; nt < 2; ++nt)
      #pragma unroll
      for (int j = 0; j < 4; ++j) acc[m][nt][j] = 0.f;

  #pragma unroll
  for (int kt = 0; kt < 4; ++kt) {
    short8 af[4];
    #pragma unroll
    for (int m = 0; m < 4; ++m) {
      const float* p = up + (size_t)(m * 16 + lr) * DM + kt * 32 + lh * 8;
      float4 v0 = *(const float4*)p;
      float4 v1 = *(const float4*)(p + 4);
      af[m] = pack8(v0, v1);
    }
    #pragma unroll
    for (int m = 0; m < 4; ++m)
      #pragma unroll
      for (int nt = 0; nt < 2; ++nt)
        acc[m][nt] = __builtin_amdgcn_mfma_f32_16x16x32_bf16(af[m], bfr[kt][nt], acc[m][nt], 0, 0, 0);
  }

  // hand Bu to the scan via LDS
  __shared__ __align__(16) float sBu[CL * 33];            // 8448B
  __shared__ __align__(16) unsigned short sSt[CL * SD];   // 4096B
  #pragma unroll
  for (int m = 0; m < 4; ++m)
    #pragma unroll
    for (int nt = 0; nt < 2; ++nt)
      #pragma unroll
      for (int j = 0; j < 4; ++j) {
        int t = m * 16 + lh * 4 + j;   // C/D: row = (lane>>4)*4 + j
        int n = nt * 16 + lr;          //      col = lane&15
        sBu[t * 33 + n] = acc[m][nt][j];
      }
  __syncthreads();

  float* carry = (float*)(ws + WS_CARRY);
  if (l < SD) {
    float s = 0.f;
    #pragma unroll
    for (int t = 0; t < CL; ++t) {
      s = fmaf(s, a_scan, sBu[t * 33 + l]);
      sSt[t * SD + l] = f2bf(s);
    }
    carry[((b * NC + c) * NG + g) * SD + l] = s;
  }
  __syncthreads();

  // states -> global (bf16), coalesced
  unsigned short* stg = (unsigned short*)(ws + WS_STL) + ((size_t)((b * NC + c) * NG + g)) * CL * SD;
  #pragma unroll
  for (int p = 0; p < 4; ++p) {
    int off = (p * 64 + l) * 8;        // 2048 ushorts
    *(short8*)(stg + off) = *(short8*)(sSt + off);
  }

  // 8 special blocks (b==0,c==0) emit the powA table for KB
  if (b == 0 && c == 0 && l < SD) {
    float* powA = (float*)(ws + WS_POWA);
    float p = 1.f;
    #pragma unroll
    for (int t = 0; t < CL; ++t) {
      p *= a_scan;
      powA[(g * CL + t) * SD + l] = p;
    }
  }
}

// ---------------- KB: chunk prefix + correction + C GEMM (swapped) + Dp*u + y ----------------
__global__ __launch_bounds__(64) void kb_y(const float* __restrict__ u,
                                           const float* __restrict__ state0,
                                           const float* __restrict__ C,
                                           const float* __restrict__ Dp,
                                           unsigned char* __restrict__ ws,
                                           float* __restrict__ y,
                                           float* __restrict__ sfin) {
  const int bx = blockIdx.x;
  const int c = bx & (NC - 1);
  const int g = (bx >> 6) & (NG - 1);
  const int b = bx >> 9;
  const int l = threadIdx.x;
  const int lr = l & 15, lh = l >> 4;
  const int n = l & 31;

  const float* powA = (const float*)(ws + WS_POWA) + g * CL * SD;
  const float* carry = (const float*)(ws + WS_CARRY);
  const unsigned short* stg = (const unsigned short*)(ws + WS_STL) + ((size_t)((b * NC + c) * NG + g)) * CL * SD;

  // --- chunk-entry prefix for this (b,c,g), per-lane n ---
  const float aL = powA[(CL - 1) * SD + n];
  float p = state0[(b * NG + g) * SD + n];
  {
    int cc = 0;
    while (cc + 8 <= c) {
      float ca[8];
      #pragma unroll
      for (int e = 0; e < 8; ++e)
        ca[e] = carry[((b * NC + cc + e) * NG + g) * SD + n];
      #pragma unroll
      for (int e = 0; e < 8; ++e) p = fmaf(p, aL, ca[e]);
      cc += 8;
    }
    for (; cc < c; ++cc)
      p = fmaf(p, aL, carry[((b * NC + cc) * NG + g) * SD + n]);
  }
  __shared__ float sPref[SD];
  if (l < SD) sPref[l] = p;
  if (c == NC - 1 && l < SD)
    sfin[(b * NG + g) * SD + l] = fmaf(p, aL, carry[((b * NC + (NC - 1)) * NG + g) * SD + l]);
  __syncthreads();

  // --- corrected state fragments (B operand, col = t, k = n) ---
  // s_true[t][n] = s_loc + a^(t+1) * pref[n];  lane: t = tt*16+lr, n = lh*8 ..+7
  short8 sf[4];
  {
    float pr[8];
    #pragma unroll
    for (int e = 0; e < 8; ++e) pr[e] = sPref[lh * 8 + e];
    #pragma unroll
    for (int tt = 0; tt < 4; ++tt) {
      int t = tt * 16 + lr;
      short8 sl = *(const short8*)(stg + t * SD + lh * 8);
      const float* pw = powA + t * SD + lh * 8;
      float4 pw0 = *(const float4*)pw;
      float4 pw1 = *(const float4*)(pw + 4);
      short8 hh;
      hh[0] = (short)f2bf(bf2f((unsigned short)sl[0]) + pw0.x * pr[0]);
      hh[1] = (short)f2bf(bf2f((unsigned short)sl[1]) + pw0.y * pr[1]);
      hh[2] = (short)f2bf(bf2f((unsigned short)sl[2]) + pw0.z * pr[2]);
      hh[3] = (short)f2bf(bf2f((unsigned short)sl[3]) + pw0.w * pr[3]);
      hh[4] = (short)f2bf(bf2f((unsigned short)sl[4]) + pw1.x * pr[4]);
      hh[5] = (short)f2bf(bf2f((unsigned short)sl[5]) + pw1.y * pr[5]);
      hh[6] = (short)f2bf(bf2f((unsigned short)sl[6]) + pw1.z * pr[6]);
      hh[7] = (short)f2bf(bf2f((unsigned short)sl[7]) + pw1.w * pr[7]);
      sf[tt] = hh;
    }
  }

  // --- GEMM with swapped operands: D[d][t] = sum_n C[d][n] * s[t][n] ---
  // A operand rows = d (lane: d = dt*16+lr, k = n = lh*8..+7), so lane's 4 acc
  // values are CONSECUTIVE d -> float4 epilogue.
  const float* cp = C + (size_t)g * GD * SD;
  const size_t rowbase = ((size_t)b * TT + (size_t)c * CL) * DM + g * GD;

  #pragma unroll
  for (int h = 0; h < 2; ++h) {
    short8 cf[4];
    #pragma unroll
    for (int dd = 0; dd < 4; ++dd) {
      int d = (h * 4 + dd) * 16 + lr;
      const float* pp = cp + (size_t)d * SD + lh * 8;
      float4 v0 = *(const float4*)pp;
      float4 v1 = *(const float4*)(pp + 4);
      cf[dd] = pack8(v0, v1);
    }
    f32x4 acc[4][4];
    #pragma unroll
    for (int dd = 0; dd < 4; ++dd)
      #pragma unroll
      for (int tt = 0; tt < 4; ++tt) {
        #pragma unroll
        for (int j = 0; j < 4; ++j) acc[dd][tt][j] = 0.f;
        acc[dd][tt] = __builtin_amdgcn_mfma_f32_16x16x32_bf16(cf[dd], sf[tt], acc[dd][tt], 0, 0, 0);
      }
    // epilogue: y = Cs + Dp*u, vectorized float4
    #pragma unroll
    for (int dd = 0; dd < 4; ++dd) {
      int d0 = (h * 4 + dd) * 16 + lh * 4;
      float4 dp4 = *(const float4*)(Dp + g * GD + d0);
      #pragma unroll
      for (int tt = 0; tt < 4; ++tt) {
        int t = tt * 16 + lr;
        size_t off = rowbase + (size_t)t * DM + d0;
        float4 u4 = *(const float4*)(u + off);
        float4 r;
        r.x = acc[dd][tt][0] + dp4.x * u4.x;
        r.y = acc[dd][tt][1] + dp4.y * u4.y;
        r.z = acc[dd][tt][2] + dp4.z * u4.z;
        r.w = acc[dd][tt][3] + dp4.w * u4.w;
        *(float4*)(y + off) = r;
      }
    }
  }
}

extern "C" void kernel_launch(void* const* d_in, const int* in_sizes, int n_in,
                              void* d_out, int out_size, void* d_ws, size_t ws_size,
                              hipStream_t stream) {
  const float* u       = (const float*)d_in[0];
  const float* state0  = (const float*)d_in[1];
  const float* A_log   = (const float*)d_in[2];
  const float* B_param = (const float*)d_in[3];
  const float* C       = (const float*)d_in[4];
  const float* Dp      = (const float*)d_in[5];
  const float* dtl     = (const float*)d_in[6];
  float* y = (float*)d_out;
  unsigned char* ws = (unsigned char*)d_ws;
  float* sfin = y + (size_t)BS * TT * DM;

  ka_bu_scan<<<dim3(BS * NG * NC), dim3(64), 0, stream>>>(u, A_log, B_param, dtl, ws);
  kb_y<<<dim3(BS * NG * NC), dim3(64), 0, stream>>>(u, state0, C, Dp, ws, y, sfin);
}